// Round 14
// baseline (510.122 us; speedup 1.0000x reference)
//
#include <hip/hip_runtime.h>
#include <math.h>

#define NNODES 50000
#define FIN 768
#define HDIM 128
#define NEDGE 400000
#define NSB 49  // ceil(50000/1024)

typedef _Float16 half8 __attribute__((ext_vector_type(8)));
typedef _Float16 half4 __attribute__((ext_vector_type(4)));
typedef _Float16 half2v __attribute__((ext_vector_type(2)));
typedef float f32x4 __attribute__((ext_vector_type(4)));

__device__ __forceinline__ void gld_lds16(const void* g, void* l) {
    __builtin_amdgcn_global_load_lds((const __attribute__((address_space(1))) unsigned int*)g,
                                     (__attribute__((address_space(3))) unsigned int*)l, 16, 0, 0);
}

__device__ __forceinline__ float gelu1(float x) {
    return 0.5f * x * (1.0f + erff(x * 0.70710678118654752f));
}

// ---------------- CSR build ----------------

__global__ __launch_bounds__(256) void count2_kernel(const int* __restrict__ ei0, const int* __restrict__ ei1,
                                                     int* __restrict__ deg0, int* __restrict__ deg1) {
    int e = blockIdx.x * 256 + threadIdx.x;
    const int* ei = blockIdx.y ? ei1 : ei0;
    int* deg = blockIdx.y ? deg1 : deg0;
    if (e < NEDGE) atomicAdd(&deg[ei[NEDGE + e]], 1);
}

__global__ __launch_bounds__(1024) void scan1_kernel(const int* __restrict__ deg0, const int* __restrict__ deg1,
                                                     int* __restrict__ ptr0, int* __restrict__ ptr1,
                                                     int* __restrict__ sums) {
    const int r = blockIdx.y;
    const int* deg = r ? deg1 : deg0;
    int* ptr = r ? ptr1 : ptr0;
    const int b = blockIdx.x, t = threadIdx.x, i = b * 1024 + t;
    __shared__ int buf[1024];
    int v = (i < NNODES) ? deg[i] : 0;
    buf[t] = v;
    __syncthreads();
    for (int off = 1; off < 1024; off <<= 1) {
        int x = (t >= off) ? buf[t - off] : 0;
        __syncthreads();
        buf[t] += x;
        __syncthreads();
    }
    if (i < NNODES) ptr[i] = buf[t] - v;
    if (t == 1023) sums[r * 64 + b] = buf[1023];
}

__global__ __launch_bounds__(64) void scan2_kernel(int* __restrict__ sums,
                                                   int* __restrict__ ptr0, int* __restrict__ ptr1) {
    const int r = blockIdx.x, t = threadIdx.x;
    int orig = (t < NSB) ? sums[r * 64 + t] : 0;
    int v = orig;
    #pragma unroll
    for (int off = 1; off < 64; off <<= 1) {
        int u = __shfl_up(v, off, 64);
        if (t >= off) v += u;
    }
    if (t < NSB) sums[r * 64 + t] = v - orig;
    if (t == NSB - 1) (r ? ptr1 : ptr0)[NNODES] = v;
}

__global__ __launch_bounds__(1024) void scan3_kernel(const int* __restrict__ sums,
                                                     int* __restrict__ ptr0, int* __restrict__ ptr1) {
    const int r = blockIdx.y;
    int* ptr = r ? ptr1 : ptr0;
    const int i = blockIdx.x * 1024 + threadIdx.x;
    if (i < NNODES) ptr[i] += sums[r * 64 + blockIdx.x];
}

__global__ __launch_bounds__(256) void scatter2_kernel(const int* __restrict__ ei0, const int* __restrict__ ei1,
                                                       const int* __restrict__ ptr0, const int* __restrict__ ptr1,
                                                       int* __restrict__ fill0, int* __restrict__ fill1,
                                                       int* __restrict__ csr0, int* __restrict__ csr1) {
    int e = blockIdx.x * 256 + threadIdx.x;
    const int* ei = blockIdx.y ? ei1 : ei0;
    const int* ptr = blockIdx.y ? ptr1 : ptr0;
    int* fill = blockIdx.y ? fill1 : fill0;
    int* csr = blockIdx.y ? csr1 : csr0;
    if (e < NEDGE) {
        int s = ei[e], d = ei[NEDGE + e];
        int p = atomicAdd(&fill[d], 1);
        csr[ptr[d] + p] = s;
    }
}

// ---------------- batched 128x128x128 f32 weight combines ----------------
__global__ __launch_bounds__(256) void gemm_cmb_kernel(
    const float* __restrict__ Wk, const float* __restrict__ Wv,
    const float* __restrict__ A0v, const float* __restrict__ M0v,
    const float* __restrict__ A1v, const float* __restrict__ M1v,
    float* __restrict__ WkA0, float* __restrict__ WvM0,
    float* __restrict__ WkA1, float* __restrict__ WvM1)
{
    const int z = blockIdx.z;
    const float* A = (z & 1) ? Wv : Wk;
    const float* B = (z == 0) ? A0v : (z == 1) ? M0v : (z == 2) ? A1v : M1v;
    float* C = (z == 0) ? WkA0 : (z == 1) ? WvM0 : (z == 2) ? WkA1 : WvM1;
    const int N = 128, K = 128;
    __shared__ float As[16][64];
    __shared__ float Bs[16][64];
    const int t = threadIdx.x;
    const int tx = t & 15, ty = t >> 4;
    const int bm = blockIdx.x * 64, bn = blockIdx.y * 64;
    const int ar = t >> 2, ac = (t & 3) << 2;
    const int br = t >> 4, bc = (t & 15) << 2;
    float acc[4][4] = {};
    for (int kb = 0; kb < K; kb += 16) {
        float4 av = *reinterpret_cast<const float4*>(A + (size_t)(bm + ar) * K + kb + ac);
        float4 bv = *reinterpret_cast<const float4*>(B + (size_t)(kb + br) * N + bn + bc);
        __syncthreads();
        As[ac + 0][ar] = av.x; As[ac + 1][ar] = av.y; As[ac + 2][ar] = av.z; As[ac + 3][ar] = av.w;
        *reinterpret_cast<float4*>(&Bs[br][bc]) = bv;
        __syncthreads();
        #pragma unroll
        for (int kk = 0; kk < 16; ++kk) {
            float4 a = *reinterpret_cast<const float4*>(&As[kk][ty << 2]);
            float4 b = *reinterpret_cast<const float4*>(&Bs[kk][tx << 2]);
            float am[4] = {a.x, a.y, a.z, a.w};
            float bb[4] = {b.x, b.y, b.z, b.w};
            #pragma unroll
            for (int i = 0; i < 4; ++i)
                #pragma unroll
                for (int j = 0; j < 4; ++j)
                    acc[i][j] = fmaf(am[i], bb[j], acc[i][j]);
        }
    }
    #pragma unroll
    for (int i = 0; i < 4; ++i)
        #pragma unroll
        for (int j = 0; j < 4; ++j)
            C[(size_t)(bm + (ty << 2) + i) * N + bn + (tx << 2) + j] = acc[i][j];
}

__global__ __launch_bounds__(128) void bias_cmb_kernel(
    const float* __restrict__ bk, const float* __restrict__ bv,
    const float* __restrict__ A0v, const float* __restrict__ M0v,
    const float* __restrict__ A1v, const float* __restrict__ M1v,
    float* __restrict__ bqkv)
{
    const int z = blockIdx.x;
    const int j = threadIdx.x;
    const float* b = (z & 1) ? bv : bk;
    const float* Mtx = (z == 0) ? A0v : (z == 1) ? M0v : (z == 2) ? A1v : M1v;
    float s = 0.f;
    for (int i = 0; i < HDIM; ++i) s += b[i] * Mtx[i * HDIM + j];
    const int r = z >> 1, kv = z & 1;
    bqkv[128 + r * 256 + ((j >> 1) << 2) + (kv << 1) + (j & 1)] = s;
}

// ---------------- weight packing ----------------
// qkv row layout: [q: 0..127][rel0: 128..383 as quads k2j,k2j+1,v2j,v2j+1][rel1: 384..639 same]
__global__ __launch_bounds__(128) void pack_qkvT(
    const float* __restrict__ Wq,   const float* __restrict__ WkA0, const float* __restrict__ WvM0,
    const float* __restrict__ WkA1, const float* __restrict__ WvM1,
    const float* __restrict__ bq,
    _Float16* __restrict__ WT, float* __restrict__ bb)
{
    int n = blockIdx.x;
    int k = threadIdx.x;
    int seg = n >> 7, col = n & 127;
    const float* W = (seg == 0) ? Wq : (seg == 1) ? WkA0 : (seg == 2) ? WvM0 : (seg == 3) ? WkA1 : WvM1;
    int np;
    if (seg == 0) np = col;
    else {
        int r = (seg - 1) >> 1, kv = (seg - 1) & 1;
        np = 128 + r * 256 + ((col >> 1) << 2) + (kv << 1) + (col & 1);
    }
    WT[(size_t)np * 128 + k] = (_Float16)W[(size_t)k * 128 + col];
    if (seg == 0 && k == 0) bb[col] = bq[col];
}

__global__ void transpose_h(const float* __restrict__ W, _Float16* __restrict__ WT, int K, int N) {
    int n = blockIdx.x, k = threadIdx.x;
    WT[(size_t)n * K + k] = (_Float16)W[(size_t)k * N + n];
}

// ---------------- fp16 MFMA GEMM (BM=128, 1-phase): C[M,N] = epi(A @ Bt^T + bias) ----------------
// ATYPE: 0 = fp16 A, 1 = f32 A. MODE 0: +bias; MODE 1: leaky; MODE 2: skip-mix with Dh.
template<int MODE, int ATYPE, bool GELU>
__global__ __launch_bounds__(256) void gemm_h(
    const void* __restrict__ Av, const _Float16* __restrict__ Bt,
    const float* __restrict__ bias, const _Float16* __restrict__ Dh,
    const float* __restrict__ gate, _Float16* __restrict__ C,
    int M, int N, int K)
{
    __shared__ _Float16 sA[4096];
    __shared__ _Float16 sB[4096];
    const int t = threadIdx.x;
    const int w = t >> 6, lane = t & 63;
    const int wm = w >> 1, wn = w & 1;
    const int bm = blockIdx.x * 128, bn = blockIdx.y * 128;
    const f32x4 zero = {0.f, 0.f, 0.f, 0.f};
    f32x4 acc[4][4];
    #pragma unroll
    for (int i = 0; i < 4; ++i)
        #pragma unroll
        for (int j = 0; j < 4; ++j) acc[i][j] = zero;

    for (int kb = 0; kb < K; kb += 32) {
        #pragma unroll
        for (int it = 0; it < 2; ++it) {
            const int c = it * 256 + t;
            const int l = c & 63;
            const int row = ((c >> 6) << 4) | (l & 15);
            const int kc = (l >> 4) << 3;
            const int cb = it * 256 + (t & 192);
            int arow = bm + row; if (arow > M - 1) arow = M - 1;
            int brow = bn + row; if (brow > N - 1) brow = N - 1;
            if (ATYPE == 1) {
                const float* ap = (const float*)Av + (size_t)arow * K + kb + kc;
                f32x4 v0 = *(const f32x4*)ap;
                f32x4 v1 = *(const f32x4*)(ap + 4);
                float tmp[8] = {v0[0], v0[1], v0[2], v0[3], v1[0], v1[1], v1[2], v1[3]};
                half8 av;
                #pragma unroll
                for (int j = 0; j < 8; ++j) {
                    float x = tmp[j];
                    if (GELU) x = gelu1(x);
                    av[j] = (_Float16)x;
                }
                *(half8*)(sA + (size_t)c * 8) = av;
            } else if (GELU) {
                half8 hv = *(const half8*)((const _Float16*)Av + (size_t)arow * K + kb + kc);
                half8 av;
                #pragma unroll
                for (int j = 0; j < 8; ++j) av[j] = (_Float16)gelu1((float)hv[j]);
                *(half8*)(sA + (size_t)c * 8) = av;
            } else {
                gld_lds16((const _Float16*)Av + (size_t)arow * K + kb + kc, sA + (size_t)cb * 8);
            }
            gld_lds16(Bt + (size_t)brow * K + kb + kc, sB + (size_t)cb * 8);
        }
        __syncthreads();
        half8 af[4], bf[4];
        #pragma unroll
        for (int i = 0; i < 4; ++i) af[i] = *(const half8*)(sA + ((size_t)((wm * 4 + i) * 64 + lane)) * 8);
        #pragma unroll
        for (int i = 0; i < 4; ++i) bf[i] = *(const half8*)(sB + ((size_t)((wn * 4 + i) * 64 + lane)) * 8);
        #pragma unroll
        for (int i = 0; i < 4; ++i)
            #pragma unroll
            for (int j = 0; j < 4; ++j)
                acc[i][j] = __builtin_amdgcn_mfma_f32_16x16x32_f16(af[i], bf[j], acc[i][j], 0, 0, 0);
        __syncthreads();
    }

    float be = 0.f;
    if (MODE == 2) be = 1.0f / (1.0f + __expf(-gate[0]));
    const int crow0 = bm + wm * 64;
    const int ccol0 = bn + wn * 64;
    #pragma unroll
    for (int i = 0; i < 4; ++i) {
        #pragma unroll
        for (int j = 0; j < 4; ++j) {
            const int col = ccol0 + j * 16 + (lane & 15);
            if (col >= N) continue;
            #pragma unroll
            for (int r = 0; r < 4; ++r) {
                const int row = crow0 + i * 16 + ((lane >> 4) << 2) + r;
                if (row >= M) continue;
                float val = acc[i][j][r] + bias[col];
                if (MODE == 1) val = (val >= 0.f) ? val : 0.01f * val;
                if (MODE == 2) val = be * val + (1.f - be) * (float)Dh[(size_t)row * HDIM + col];
                C[(size_t)row * N + col] = (_Float16)val;
            }
        }
    }
}

// ---------------- fp16 MFMA GEMM (BM=16, BN=128, BK=64, 1-phase) ----------------
// 3125 blocks -> ~12/CU, 18KB LDS -> 8 blocks/CU resident (full occupancy).
// All 4 waves SHARE the block's 2 A-frags; wave w owns output cols [w*32, w*32+32).
// ATYPE: 0 = fp16 A, 1 = f32 A.
template<int MODE, int ATYPE, bool GELU>
__global__ __launch_bounds__(256) void gemm_h16(
    const void* __restrict__ Av, const _Float16* __restrict__ Bt,
    const float* __restrict__ bias, const _Float16* __restrict__ Dh,
    const float* __restrict__ gate, _Float16* __restrict__ C,
    int M, int N, int K)
{
    __shared__ _Float16 sA[2 * 64 * 8];   // 2 k-frags (16 rows), 2KB
    __shared__ _Float16 sB[16 * 64 * 8];  // 4 waves x (2 ni x 2 kk), 16KB
    const int t = threadIdx.x;
    const int w = t >> 6, lane = t & 63;
    const int rl = lane & 15, kg = lane >> 4;
    const int bm = blockIdx.x * 16;
    const f32x4 zero = {0.f, 0.f, 0.f, 0.f};
    f32x4 acc[2] = {zero, zero};

    int arow = bm + rl; if (arow > M - 1) arow = M - 1;
    int nrowB[4];
    #pragma unroll
    for (int j = 0; j < 4; ++j) {
        int nr = w * 32 + ((j >> 1) & 1) * 16 + rl;
        nrowB[j] = (nr < N) ? nr : N - 1;
    }

    for (int kb = 0; kb < K; kb += 64) {
        // A: waves 0,1 stage frag kk=w
        if (w < 2) {
            const int ko = kb + w * 32 + kg * 8;
            if (ATYPE == 1) {
                const float* ap = (const float*)Av + (size_t)arow * K + ko;
                f32x4 v0 = *(const f32x4*)ap;
                f32x4 v1 = *(const f32x4*)(ap + 4);
                float tmp[8] = {v0[0], v0[1], v0[2], v0[3], v1[0], v1[1], v1[2], v1[3]};
                half8 av;
                #pragma unroll
                for (int j = 0; j < 8; ++j) {
                    float x = tmp[j];
                    if (GELU) x = gelu1(x);
                    av[j] = (_Float16)x;
                }
                *(half8*)(sA + (size_t)(w * 64 + lane) * 8) = av;
            } else if (GELU) {
                half8 hv = *(const half8*)((const _Float16*)Av + (size_t)arow * K + ko);
                half8 av;
                #pragma unroll
                for (int j = 0; j < 8; ++j) av[j] = (_Float16)gelu1((float)hv[j]);
                *(half8*)(sA + (size_t)(w * 64 + lane) * 8) = av;
            } else {
                gld_lds16((const _Float16*)Av + (size_t)arow * K + ko, sA + (size_t)(w * 64) * 8);
            }
        }
        // B: wave w stages its 4 frags
        #pragma unroll
        for (int j = 0; j < 4; ++j) {
            const int kk = j & 1;
            gld_lds16(Bt + (size_t)nrowB[j] * K + kb + kk * 32 + kg * 8,
                      sB + (size_t)((w * 4 + j) * 64) * 8);
        }
        __syncthreads();
        half8 af[2], bf[2][2];
        #pragma unroll
        for (int kk = 0; kk < 2; ++kk)
            af[kk] = *(const half8*)(sA + (size_t)(kk * 64 + lane) * 8);
        #pragma unroll
        for (int ni = 0; ni < 2; ++ni)
            #pragma unroll
            for (int kk = 0; kk < 2; ++kk)
                bf[ni][kk] = *(const half8*)(sB + (size_t)((w * 4 + ni * 2 + kk) * 64 + lane) * 8);
        #pragma unroll
        for (int ni = 0; ni < 2; ++ni)
            #pragma unroll
            for (int kk = 0; kk < 2; ++kk)
                acc[ni] = __builtin_amdgcn_mfma_f32_16x16x32_f16(af[kk], bf[ni][kk], acc[ni], 0, 0, 0);
        __syncthreads();
    }

    float be = 0.f;
    if (MODE == 2) be = 1.0f / (1.0f + __expf(-gate[0]));
    #pragma unroll
    for (int ni = 0; ni < 2; ++ni) {
        const int col = w * 32 + ni * 16 + rl;
        if (col >= N) continue;
        #pragma unroll
        for (int r = 0; r < 4; ++r) {
            const int row = bm + kg * 4 + r;
            if (row >= M) continue;
            float val = acc[ni][r] + bias[col];
            if (MODE == 1) val = (val >= 0.f) ? val : 0.01f * val;
            if (MODE == 2) val = be * val + (1.f - be) * (float)Dh[(size_t)row * HDIM + col];
            C[(size_t)row * N + col] = (_Float16)val;
        }
    }
}

// ---------------- fused two-relation per-dst softmax attention ----------------
// wave per dst; lane owns channel pair (2l, 2l+1); 8-edge unroll; no max-shift
// (alpha = p * q.k/sqrt(128) is O(1) << 88 -> plain expf f32-safe; softmax shift-invariant)
__global__ __launch_bounds__(256) void attn2_kernel(
    const _Float16* __restrict__ qkv,
    const int* __restrict__ ptr0, const int* __restrict__ csr0,
    const int* __restrict__ ptr1, const int* __restrict__ csr1,
    const float* __restrict__ p0, const float* __restrict__ p1,
    _Float16* __restrict__ att)
{
    const int w = (blockIdx.x * 256 + threadIdx.x) >> 6;
    if (w >= NNODES) return;
    const int lane = threadIdx.x & 63;
    half2v qh = *(const half2v*)(qkv + (size_t)w * 640 + (lane << 1));
    const float qx = (float)qh[0], qy = (float)qh[1];
    float ox = 0.f, oy = 0.f;
    #pragma unroll
    for (int r = 0; r < 2; ++r) {
        const int* ptrv = r ? ptr1 : ptr0;
        const int* csr  = r ? csr1 : csr0;
        const float scale = (r ? p1[0] : p0[0]) * 0.08838834764831845f;
        const int start = ptrv[w], end = ptrv[w + 1];
        if (start == end) continue;
        const _Float16* tbl = qkv + 128 + 256 * r + (lane << 2);
        float denom = 0.f, ax = 0.f, ay = 0.f;
        int i = start;
        for (; i + 8 <= end; i += 8) {
            int s[8];
            #pragma unroll
            for (int j = 0; j < 8; ++j) s[j] = csr[i + j];
            half4 kv[8];
            #pragma unroll
            for (int j = 0; j < 8; ++j) kv[j] = *(const half4*)(tbl + (size_t)s[j] * 640);
            float d[8];
            #pragma unroll
            for (int j = 0; j < 8; ++j) d[j] = qx * (float)kv[j][0] + qy * (float)kv[j][1];
            #pragma unroll
            for (int o2 = 32; o2; o2 >>= 1) {
                #pragma unroll
                for (int j = 0; j < 8; ++j) d[j] += __shfl_xor(d[j], o2, 64);
            }
            #pragma unroll
            for (int j = 0; j < 8; ++j) {
                const float e = __expf(d[j] * scale);
                denom += e;
                ax += e * (float)kv[j][2];
                ay += e * (float)kv[j][3];
            }
        }
        for (; i + 4 <= end; i += 4) {
            const int s0 = csr[i], s1 = csr[i + 1], s2 = csr[i + 2], s3 = csr[i + 3];
            half4 kv0 = *(const half4*)(tbl + (size_t)s0 * 640);
            half4 kv1 = *(const half4*)(tbl + (size_t)s1 * 640);
            half4 kv2 = *(const half4*)(tbl + (size_t)s2 * 640);
            half4 kv3 = *(const half4*)(tbl + (size_t)s3 * 640);
            float d0 = qx * (float)kv0[0] + qy * (float)kv0[1];
            float d1 = qx * (float)kv1[0] + qy * (float)kv1[1];
            float d2 = qx * (float)kv2[0] + qy * (float)kv2[1];
            float d3 = qx * (float)kv3[0] + qy * (float)kv3[1];
            #pragma unroll
            for (int o2 = 32; o2; o2 >>= 1) {
                d0 += __shfl_xor(d0, o2, 64);
                d1 += __shfl_xor(d1, o2, 64);
                d2 += __shfl_xor(d2, o2, 64);
                d3 += __shfl_xor(d3, o2, 64);
            }
            const float e0 = __expf(d0 * scale), e1 = __expf(d1 * scale);
            const float e2 = __expf(d2 * scale), e3 = __expf(d3 * scale);
            denom += (e0 + e1) + (e2 + e3);
            ax += e0 * (float)kv0[2] + e1 * (float)kv1[2] + e2 * (float)kv2[2] + e3 * (float)kv3[2];
            ay += e0 * (float)kv0[3] + e1 * (float)kv1[3] + e2 * (float)kv2[3] + e3 * (float)kv3[3];
        }
        for (; i < end; ++i) {
            const int s = csr[i];
            half4 kv = *(const half4*)(tbl + (size_t)s * 640);
            float d = qx * (float)kv[0] + qy * (float)kv[1];
            #pragma unroll
            for (int o2 = 32; o2; o2 >>= 1) d += __shfl_xor(d, o2, 64);
            const float e = __expf(d * scale);
            denom += e;
            ax += e * (float)kv[2];
            ay += e * (float)kv[3];
        }
        const float inv = 1.0f / denom;
        ox += ax * inv; oy += ay * inv;
    }
    half2v o;
    o[0] = (_Float16)ox;
    o[1] = (_Float16)oy;
    *(half2v*)(att + (size_t)w * HDIM + (lane << 1)) = o;
}

// ---------------- tiny head tail ----------------
__global__ __launch_bounds__(256) void head2_kernel(const _Float16* __restrict__ h,
                                                    const float* __restrict__ Wo2,
                                                    const float* __restrict__ bo2,
                                                    float* __restrict__ out)
{
    int i = blockIdx.x * 256 + threadIdx.x;
    if (i >= NNODES) return;
    const _Float16* hp = h + (size_t)i * 64;
    float s0 = bo2[0], s1 = bo2[1];
    #pragma unroll
    for (int j0 = 0; j0 < 64; j0 += 8) {
        half8 hv = *(const half8*)(hp + j0);
        #pragma unroll
        for (int j = 0; j < 8; ++j) {
            float v = (float)hv[j];
            s0 += v * Wo2[2 * (j0 + j)];
            s1 += v * Wo2[2 * (j0 + j) + 1];
        }
    }
    out[2 * i] = s0;
    out[2 * i + 1] = s1;
}

// ---------------- launch ----------------

extern "C" void kernel_launch(void* const* d_in, const int* in_sizes, int n_in,
                              void* d_out, int out_size, void* d_ws, size_t ws_size,
                              hipStream_t stream)
{
    const float* features = (const float*)d_in[0];
    const int* ei0 = (const int*)d_in[1];
    const int* ei1 = (const int*)d_in[2];
    const float* W1 = (const float*)d_in[3];
    const float* b1 = (const float*)d_in[4];
    const float* Wk = (const float*)d_in[5];
    const float* bk = (const float*)d_in[6];
    const float* Wq = (const float*)d_in[7];
    const float* bq = (const float*)d_in[8];
    const float* Wv = (const float*)d_in[9];
    const float* bv = (const float*)d_in[10];
    const float* A0 = (const float*)d_in[11];
    const float* M0 = (const float*)d_in[12];
    const float* p0 = (const float*)d_in[13];
    const float* A1 = (const float*)d_in[14];
    const float* M1 = (const float*)d_in[15];
    const float* p1 = (const float*)d_in[16];
    const float* Wa = (const float*)d_in[17];
    const float* ba = (const float*)d_in[18];
    const float* skip = (const float*)d_in[19];
    const float* Wo1 = (const float*)d_in[20];
    const float* bo1 = (const float*)d_in[21];
    const float* Wo2 = (const float*)d_in[22];
    const float* bo2 = (const float*)d_in[23];
    (void)in_sizes; (void)n_in; (void)out_size; (void)ws_size;

    char* base = (char*)d_ws;
    size_t off = 0;
    auto alloc = [&](size_t bytes) { size_t r = off; off = (off + bytes + 255) & ~(size_t)255; return base + r; };

    _Float16* x0h  = (_Float16*)alloc((size_t)NNODES * HDIM * 2);
    _Float16* x1h  = (_Float16*)alloc((size_t)NNODES * HDIM * 2);
    _Float16* qkv  = (_Float16*)alloc((size_t)NNODES * 640 * 2);
    _Float16* att  = (_Float16*)alloc((size_t)NNODES * HDIM * 2);
    _Float16* hh   = (_Float16*)alloc((size_t)NNODES * 64 * 2);
    float* WkA[2]  = { (float*)alloc(65536), (float*)alloc(65536) };
    float* WvM[2]  = { (float*)alloc(65536), (float*)alloc(65536) };
    _Float16* WqkvT = (_Float16*)alloc(640 * 128 * 2);
    float*    bqkv  = (float*)   alloc(640 * 4);
    _Float16* W1T   = (_Float16*)alloc(128 * 768 * 2);
    _Float16* WaT   = (_Float16*)alloc(128 * 128 * 2);
    _Float16* Wo1T  = (_Float16*)alloc(64 * 128 * 2);
    int* deg[2]  = { (int*)alloc(NNODES * 4), (int*)alloc(NNODES * 4) };
    int* ptrv[2] = { (int*)alloc((NNODES + 1) * 4), (int*)alloc((NNODES + 1) * 4) };
    int* fill[2] = { (int*)alloc(NNODES * 4), (int*)alloc(NNODES * 4) };
    int* csr[2]  = { (int*)alloc(NEDGE * 4),  (int*)alloc(NEDGE * 4) };
    int* sums    = (int*)alloc(2 * 64 * 4);

    // ---- CSR build ----
    hipMemsetAsync(deg[0], 0, NNODES * 4, stream);
    hipMemsetAsync(deg[1], 0, NNODES * 4, stream);
    hipMemsetAsync(fill[0], 0, NNODES * 4, stream);
    hipMemsetAsync(fill[1], 0, NNODES * 4, stream);
    const int egrid = (NEDGE + 255) / 256;
    count2_kernel<<<dim3(egrid, 2), 256, 0, stream>>>(ei0, ei1, deg[0], deg[1]);
    scan1_kernel<<<dim3(NSB, 2), 1024, 0, stream>>>(deg[0], deg[1], ptrv[0], ptrv[1], sums);
    scan2_kernel<<<2, 64, 0, stream>>>(sums, ptrv[0], ptrv[1]);
    scan3_kernel<<<dim3(NSB, 2), 1024, 0, stream>>>(sums, ptrv[0], ptrv[1]);
    scatter2_kernel<<<dim3(egrid, 2), 256, 0, stream>>>(ei0, ei1, ptrv[0], ptrv[1],
                                                        fill[0], fill[1], csr[0], csr[1]);

    // ---- combined relation weights + biases ----
    gemm_cmb_kernel<<<dim3(2, 2, 4), 256, 0, stream>>>(Wk, Wv, A0, M0, A1, M1,
                                                       WkA[0], WvM[0], WkA[1], WvM[1]);
    bias_cmb_kernel<<<4, 128, 0, stream>>>(bk, bv, A0, M0, A1, M1, bqkv);

    // ---- pack fp16 transposed weights ----
    pack_qkvT<<<640, 128, 0, stream>>>(Wq, WkA[0], WvM[0], WkA[1], WvM[1], bq, WqkvT, bqkv);
    transpose_h<<<128, 768, 0, stream>>>(W1, W1T, 768, 128);
    transpose_h<<<128, 128, 0, stream>>>(Wa, WaT, 128, 128);
    transpose_h<<<64, 128, 0, stream>>>(Wo1, Wo1T, 128, 64);

    const int MBLK = (NNODES + 127) / 128;   // 391
    const int MBLK16 = (NNODES + 15) / 16;   // 3125

    // ---- x0 = leaky(features @ W1 + b1) -> fp16 ----
    gemm_h16<1, 1, false><<<MBLK16, 256, 0, stream>>>(
        features, W1T, b1, nullptr, nullptr, x0h, NNODES, HDIM, FIN);

    // ---- two HGT layers ----
    _Float16* xin = x0h;
    _Float16* xout = x1h;
    for (int layer = 0; layer < 2; ++layer) {
        gemm_h<0, 0, false><<<dim3(MBLK, 5), 256, 0, stream>>>(
            xin, WqkvT, bqkv, nullptr, nullptr, qkv, NNODES, 640, HDIM);
        attn2_kernel<<<(NNODES * 64 + 255) / 256, 256, 0, stream>>>(
            qkv, ptrv[0], csr[0], ptrv[1], csr[1], p0, p1, att);
        gemm_h16<2, 0, true><<<MBLK16, 256, 0, stream>>>(
            att, WaT, ba, xin, skip, xout, NNODES, HDIM, HDIM);
        _Float16* tmp = xin; xin = xout; xout = tmp;
    }

    // ---- head ----
    gemm_h16<1, 0, false><<<MBLK16, 256, 0, stream>>>(
        xin, Wo1T, bo1, nullptr, nullptr, hh, NNODES, 64, HDIM);
    head2_kernel<<<(NNODES + 255) / 256, 256, 0, stream>>>(hh, Wo2, bo2, (float*)d_out);
}

// Round 16
// 448.436 us; speedup vs baseline: 1.1376x; 1.1376x over previous
//
#include <hip/hip_runtime.h>
#include <math.h>

#define NNODES 50000
#define FIN 768
#define HDIM 128
#define NEDGE 400000
#define NSB 49  // ceil(50000/1024)

typedef _Float16 half8 __attribute__((ext_vector_type(8)));
typedef _Float16 half4 __attribute__((ext_vector_type(4)));
typedef _Float16 half2v __attribute__((ext_vector_type(2)));
typedef float f32x4 __attribute__((ext_vector_type(4)));

__device__ __forceinline__ void gld_lds16(const void* g, void* l) {
    __builtin_amdgcn_global_load_lds((const __attribute__((address_space(1))) unsigned int*)g,
                                     (__attribute__((address_space(3))) unsigned int*)l, 16, 0, 0);
}

__device__ __forceinline__ float gelu1(float x) {
    return 0.5f * x * (1.0f + erff(x * 0.70710678118654752f));
}

// ---------------- CSR build ----------------

__global__ __launch_bounds__(256) void count2_kernel(const int* __restrict__ ei0, const int* __restrict__ ei1,
                                                     int* __restrict__ deg0, int* __restrict__ deg1) {
    int e = blockIdx.x * 256 + threadIdx.x;
    const int* ei = blockIdx.y ? ei1 : ei0;
    int* deg = blockIdx.y ? deg1 : deg0;
    if (e < NEDGE) atomicAdd(&deg[ei[NEDGE + e]], 1);
}

__global__ __launch_bounds__(1024) void scan1_kernel(const int* __restrict__ deg0, const int* __restrict__ deg1,
                                                     int* __restrict__ ptr0, int* __restrict__ ptr1,
                                                     int* __restrict__ sums) {
    const int r = blockIdx.y;
    const int* deg = r ? deg1 : deg0;
    int* ptr = r ? ptr1 : ptr0;
    const int b = blockIdx.x, t = threadIdx.x, i = b * 1024 + t;
    __shared__ int buf[1024];
    int v = (i < NNODES) ? deg[i] : 0;
    buf[t] = v;
    __syncthreads();
    for (int off = 1; off < 1024; off <<= 1) {
        int x = (t >= off) ? buf[t - off] : 0;
        __syncthreads();
        buf[t] += x;
        __syncthreads();
    }
    if (i < NNODES) ptr[i] = buf[t] - v;
    if (t == 1023) sums[r * 64 + b] = buf[1023];
}

__global__ __launch_bounds__(64) void scan2_kernel(int* __restrict__ sums,
                                                   int* __restrict__ ptr0, int* __restrict__ ptr1) {
    const int r = blockIdx.x, t = threadIdx.x;
    int orig = (t < NSB) ? sums[r * 64 + t] : 0;
    int v = orig;
    #pragma unroll
    for (int off = 1; off < 64; off <<= 1) {
        int u = __shfl_up(v, off, 64);
        if (t >= off) v += u;
    }
    if (t < NSB) sums[r * 64 + t] = v - orig;
    if (t == NSB - 1) (r ? ptr1 : ptr0)[NNODES] = v;
}

__global__ __launch_bounds__(1024) void scan3_kernel(const int* __restrict__ sums,
                                                     int* __restrict__ ptr0, int* __restrict__ ptr1) {
    const int r = blockIdx.y;
    int* ptr = r ? ptr1 : ptr0;
    const int i = blockIdx.x * 1024 + threadIdx.x;
    if (i < NNODES) ptr[i] += sums[r * 64 + blockIdx.x];
}

__global__ __launch_bounds__(256) void scatter2_kernel(const int* __restrict__ ei0, const int* __restrict__ ei1,
                                                       const int* __restrict__ ptr0, const int* __restrict__ ptr1,
                                                       int* __restrict__ fill0, int* __restrict__ fill1,
                                                       int* __restrict__ csr0, int* __restrict__ csr1) {
    int e = blockIdx.x * 256 + threadIdx.x;
    const int* ei = blockIdx.y ? ei1 : ei0;
    const int* ptr = blockIdx.y ? ptr1 : ptr0;
    int* fill = blockIdx.y ? fill1 : fill0;
    int* csr = blockIdx.y ? csr1 : csr0;
    if (e < NEDGE) {
        int s = ei[e], d = ei[NEDGE + e];
        int p = atomicAdd(&fill[d], 1);
        csr[ptr[d] + p] = s;
    }
}

// ---------------- combined weight+bias prep: z<4 = 64x64-tiled 128^3 GEMM, z==4 = bias dots ----------------
__global__ __launch_bounds__(256) void cmb_all_kernel(
    const float* __restrict__ Wk, const float* __restrict__ Wv,
    const float* __restrict__ bk, const float* __restrict__ bv,
    const float* __restrict__ A0v, const float* __restrict__ M0v,
    const float* __restrict__ A1v, const float* __restrict__ M1v,
    float* __restrict__ WkA0, float* __restrict__ WvM0,
    float* __restrict__ WkA1, float* __restrict__ WvM1,
    float* __restrict__ bqkv)
{
    const int z = blockIdx.z;
    if (z == 4) {
        if (blockIdx.x || blockIdx.y) return;
        const int j = threadIdx.x;
        if (j >= 128) return;
        #pragma unroll
        for (int zz = 0; zz < 4; ++zz) {
            const float* b = (zz & 1) ? bv : bk;
            const float* Mtx = (zz == 0) ? A0v : (zz == 1) ? M0v : (zz == 2) ? A1v : M1v;
            float s = 0.f;
            for (int i = 0; i < HDIM; ++i) s += b[i] * Mtx[i * HDIM + j];
            bqkv[128 + (zz >> 1) * 256 + ((j >> 1) << 2) + ((zz & 1) << 1) + (j & 1)] = s;
        }
        return;
    }
    const float* A = (z & 1) ? Wv : Wk;
    const float* B = (z == 0) ? A0v : (z == 1) ? M0v : (z == 2) ? A1v : M1v;
    float* C = (z == 0) ? WkA0 : (z == 1) ? WvM0 : (z == 2) ? WkA1 : WvM1;
    const int N = 128, K = 128;
    __shared__ float As[16][64];
    __shared__ float Bs[16][64];
    const int t = threadIdx.x;
    const int tx = t & 15, ty = t >> 4;
    const int bm = blockIdx.x * 64, bn = blockIdx.y * 64;
    const int ar = t >> 2, ac = (t & 3) << 2;
    const int br = t >> 4, bc = (t & 15) << 2;
    float acc[4][4] = {};
    for (int kb = 0; kb < K; kb += 16) {
        float4 av = *reinterpret_cast<const float4*>(A + (size_t)(bm + ar) * K + kb + ac);
        float4 bv2 = *reinterpret_cast<const float4*>(B + (size_t)(kb + br) * N + bn + bc);
        __syncthreads();
        As[ac + 0][ar] = av.x; As[ac + 1][ar] = av.y; As[ac + 2][ar] = av.z; As[ac + 3][ar] = av.w;
        *reinterpret_cast<float4*>(&Bs[br][bc]) = bv2;
        __syncthreads();
        #pragma unroll
        for (int kk = 0; kk < 16; ++kk) {
            float4 a = *reinterpret_cast<const float4*>(&As[kk][ty << 2]);
            float4 b2 = *reinterpret_cast<const float4*>(&Bs[kk][tx << 2]);
            float am[4] = {a.x, a.y, a.z, a.w};
            float bb[4] = {b2.x, b2.y, b2.z, b2.w};
            #pragma unroll
            for (int i = 0; i < 4; ++i)
                #pragma unroll
                for (int j = 0; j < 4; ++j)
                    acc[i][j] = fmaf(am[i], bb[j], acc[i][j]);
        }
    }
    #pragma unroll
    for (int i = 0; i < 4; ++i)
        #pragma unroll
        for (int j = 0; j < 4; ++j)
            C[(size_t)(bm + (ty << 2) + i) * N + bn + (tx << 2) + j] = acc[i][j];
}

// ---------------- unified weight packing (960 blocks x 128 threads) ----------------
// b<640: WqkvT row (qkv permuted layout); 640..767: W1T; 768..895: WaT; 896..959: Wo1T
__global__ __launch_bounds__(128) void pack_all_kernel(
    const float* __restrict__ Wq,   const float* __restrict__ WkA0, const float* __restrict__ WvM0,
    const float* __restrict__ WkA1, const float* __restrict__ WvM1,
    const float* __restrict__ bq,   const float* __restrict__ W1,
    const float* __restrict__ Wa,   const float* __restrict__ Wo1,
    _Float16* __restrict__ WqkvT, float* __restrict__ bqkv,
    _Float16* __restrict__ W1T, _Float16* __restrict__ WaT, _Float16* __restrict__ Wo1T)
{
    const int b = blockIdx.x, k = threadIdx.x;
    if (b < 640) {
        int seg = b >> 7, col = b & 127;
        const float* W = (seg == 0) ? Wq : (seg == 1) ? WkA0 : (seg == 2) ? WvM0 : (seg == 3) ? WkA1 : WvM1;
        int np;
        if (seg == 0) np = col;
        else {
            int r = (seg - 1) >> 1, kv = (seg - 1) & 1;
            np = 128 + r * 256 + ((col >> 1) << 2) + (kv << 1) + (col & 1);
        }
        WqkvT[(size_t)np * 128 + k] = (_Float16)W[(size_t)k * 128 + col];
        if (seg == 0 && k == 0) bqkv[col] = bq[col];
    } else if (b < 768) {
        const int n = b - 640;
        for (int kk = k; kk < 768; kk += 128)
            W1T[(size_t)n * 768 + kk] = (_Float16)W1[(size_t)kk * 128 + n];
    } else if (b < 896) {
        const int n = b - 768;
        WaT[(size_t)n * 128 + k] = (_Float16)Wa[(size_t)k * 128 + n];
    } else {
        const int n = b - 896;
        Wo1T[(size_t)n * 128 + k] = (_Float16)Wo1[(size_t)k * 64 + n];
    }
}

// ---------------- fp16 MFMA GEMM (BM=128, 1-phase): C[M,N] = epi(A @ Bt^T + bias) ----------------
// ATYPE: 0 = fp16 A, 1 = f32 A. MODE 0: +bias; MODE 1: leaky; MODE 2: skip-mix with Dh.
template<int MODE, int ATYPE, bool GELU>
__global__ __launch_bounds__(256) void gemm_h(
    const void* __restrict__ Av, const _Float16* __restrict__ Bt,
    const float* __restrict__ bias, const _Float16* __restrict__ Dh,
    const float* __restrict__ gate, _Float16* __restrict__ C,
    int M, int N, int K)
{
    __shared__ _Float16 sA[4096];
    __shared__ _Float16 sB[4096];
    const int t = threadIdx.x;
    const int w = t >> 6, lane = t & 63;
    const int wm = w >> 1, wn = w & 1;
    const int bm = blockIdx.x * 128, bn = blockIdx.y * 128;
    const f32x4 zero = {0.f, 0.f, 0.f, 0.f};
    f32x4 acc[4][4];
    #pragma unroll
    for (int i = 0; i < 4; ++i)
        #pragma unroll
        for (int j = 0; j < 4; ++j) acc[i][j] = zero;

    for (int kb = 0; kb < K; kb += 32) {
        #pragma unroll
        for (int it = 0; it < 2; ++it) {
            const int c = it * 256 + t;
            const int l = c & 63;
            const int row = ((c >> 6) << 4) | (l & 15);
            const int kc = (l >> 4) << 3;
            const int cb = it * 256 + (t & 192);
            int arow = bm + row; if (arow > M - 1) arow = M - 1;
            int brow = bn + row; if (brow > N - 1) brow = N - 1;
            if (ATYPE == 1) {
                const float* ap = (const float*)Av + (size_t)arow * K + kb + kc;
                f32x4 v0 = *(const f32x4*)ap;
                f32x4 v1 = *(const f32x4*)(ap + 4);
                float tmp[8] = {v0[0], v0[1], v0[2], v0[3], v1[0], v1[1], v1[2], v1[3]};
                half8 av;
                #pragma unroll
                for (int j = 0; j < 8; ++j) {
                    float x = tmp[j];
                    if (GELU) x = gelu1(x);
                    av[j] = (_Float16)x;
                }
                *(half8*)(sA + (size_t)c * 8) = av;
            } else if (GELU) {
                half8 hv = *(const half8*)((const _Float16*)Av + (size_t)arow * K + kb + kc);
                half8 av;
                #pragma unroll
                for (int j = 0; j < 8; ++j) av[j] = (_Float16)gelu1((float)hv[j]);
                *(half8*)(sA + (size_t)c * 8) = av;
            } else {
                gld_lds16((const _Float16*)Av + (size_t)arow * K + kb + kc, sA + (size_t)cb * 8);
            }
            gld_lds16(Bt + (size_t)brow * K + kb + kc, sB + (size_t)cb * 8);
        }
        __syncthreads();
        half8 af[4], bf[4];
        #pragma unroll
        for (int i = 0; i < 4; ++i) af[i] = *(const half8*)(sA + ((size_t)((wm * 4 + i) * 64 + lane)) * 8);
        #pragma unroll
        for (int i = 0; i < 4; ++i) bf[i] = *(const half8*)(sB + ((size_t)((wn * 4 + i) * 64 + lane)) * 8);
        #pragma unroll
        for (int i = 0; i < 4; ++i)
            #pragma unroll
            for (int j = 0; j < 4; ++j)
                acc[i][j] = __builtin_amdgcn_mfma_f32_16x16x32_f16(af[i], bf[j], acc[i][j], 0, 0, 0);
        __syncthreads();
    }

    float be = 0.f;
    if (MODE == 2) be = 1.0f / (1.0f + __expf(-gate[0]));
    const int crow0 = bm + wm * 64;
    const int ccol0 = bn + wn * 64;
    #pragma unroll
    for (int i = 0; i < 4; ++i) {
        #pragma unroll
        for (int j = 0; j < 4; ++j) {
            const int col = ccol0 + j * 16 + (lane & 15);
            if (col >= N) continue;
            #pragma unroll
            for (int r = 0; r < 4; ++r) {
                const int row = crow0 + i * 16 + ((lane >> 4) << 2) + r;
                if (row >= M) continue;
                float val = acc[i][j][r] + bias[col];
                if (MODE == 1) val = (val >= 0.f) ? val : 0.01f * val;
                if (MODE == 2) val = be * val + (1.f - be) * (float)Dh[(size_t)row * HDIM + col];
                C[(size_t)row * N + col] = (_Float16)val;
            }
        }
    }
}

// ---------------- fp16 MFMA GEMM (BM=32, BN=128, BK=64, 1-phase) ----------------
// ATYPE: 0 = fp16 A, 1 = f32 A. wave w owns output cols [w*32, w*32+32)
template<int MODE, int ATYPE, bool GELU>
__global__ __launch_bounds__(256) void gemm_h32(
    const void* __restrict__ Av, const _Float16* __restrict__ Bt,
    const float* __restrict__ bias, const _Float16* __restrict__ Dh,
    const float* __restrict__ gate, _Float16* __restrict__ C,
    int M, int N, int K)
{
    __shared__ _Float16 sA[4 * 64 * 8];   // 4 frags (2m x 2k), 4KB
    __shared__ _Float16 sB[16 * 64 * 8];  // 16 frags (4w x 2n x 2k), 16KB
    const int t = threadIdx.x;
    const int w = t >> 6, lane = t & 63;
    const int rl = lane & 15, kg = lane >> 4;
    const int bm = blockIdx.x * 32;
    const f32x4 zero = {0.f, 0.f, 0.f, 0.f};
    f32x4 acc[2][2] = {{zero, zero}, {zero, zero}};

    for (int kb = 0; kb < K; kb += 64) {
        {
            const int mi = w >> 1, kk = w & 1;
            int arow = bm + mi * 16 + rl; if (arow > M - 1) arow = M - 1;
            const int ko = kb + kk * 32 + kg * 8;
            if (ATYPE == 1) {
                const float* ap = (const float*)Av + (size_t)arow * K + ko;
                f32x4 v0 = *(const f32x4*)ap;
                f32x4 v1 = *(const f32x4*)(ap + 4);
                float tmp[8] = {v0[0], v0[1], v0[2], v0[3], v1[0], v1[1], v1[2], v1[3]};
                half8 av;
                #pragma unroll
                for (int j = 0; j < 8; ++j) {
                    float x = tmp[j];
                    if (GELU) x = gelu1(x);
                    av[j] = (_Float16)x;
                }
                *(half8*)(sA + (size_t)(w * 64 + lane) * 8) = av;
            } else if (GELU) {
                half8 hv = *(const half8*)((const _Float16*)Av + (size_t)arow * K + ko);
                half8 av;
                #pragma unroll
                for (int j = 0; j < 8; ++j) av[j] = (_Float16)gelu1((float)hv[j]);
                *(half8*)(sA + (size_t)(w * 64 + lane) * 8) = av;
            } else {
                gld_lds16((const _Float16*)Av + (size_t)arow * K + ko, sA + (size_t)(w * 64) * 8);
            }
        }
        #pragma unroll
        for (int j = 0; j < 4; ++j) {
            const int fb = w * 4 + j;
            const int ni = (j >> 1) & 1, kk = j & 1;
            int nrow = w * 32 + ni * 16 + rl; if (nrow > N - 1) nrow = N - 1;
            gld_lds16(Bt + (size_t)nrow * K + kb + kk * 32 + kg * 8, sB + (size_t)(fb * 64) * 8);
        }
        __syncthreads();
        half8 af[2][2], bf[2][2];
        #pragma unroll
        for (int mi = 0; mi < 2; ++mi)
            #pragma unroll
            for (int kk = 0; kk < 2; ++kk)
                af[mi][kk] = *(const half8*)(sA + (size_t)((mi * 2 + kk) * 64 + lane) * 8);
        #pragma unroll
        for (int ni = 0; ni < 2; ++ni)
            #pragma unroll
            for (int kk = 0; kk < 2; ++kk)
                bf[ni][kk] = *(const half8*)(sB + (size_t)((w * 4 + ni * 2 + kk) * 64 + lane) * 8);
        #pragma unroll
        for (int mi = 0; mi < 2; ++mi)
            #pragma unroll
            for (int ni = 0; ni < 2; ++ni)
                #pragma unroll
                for (int kk = 0; kk < 2; ++kk)
                    acc[mi][ni] = __builtin_amdgcn_mfma_f32_16x16x32_f16(af[mi][kk], bf[ni][kk], acc[mi][ni], 0, 0, 0);
        __syncthreads();
    }

    float be = 0.f;
    if (MODE == 2) be = 1.0f / (1.0f + __expf(-gate[0]));
    #pragma unroll
    for (int mi = 0; mi < 2; ++mi) {
        #pragma unroll
        for (int ni = 0; ni < 2; ++ni) {
            const int col = w * 32 + ni * 16 + rl;
            if (col >= N) continue;
            #pragma unroll
            for (int r = 0; r < 4; ++r) {
                const int row = bm + mi * 16 + kg * 4 + r;
                if (row >= M) continue;
                float val = acc[mi][ni][r] + bias[col];
                if (MODE == 1) val = (val >= 0.f) ? val : 0.01f * val;
                if (MODE == 2) val = be * val + (1.f - be) * (float)Dh[(size_t)row * HDIM + col];
                C[(size_t)row * N + col] = (_Float16)val;
            }
        }
    }
}

// ---------------- fused two-relation per-dst softmax attention ----------------
// wave per dst; lane owns channel pair (2l, 2l+1); 8-edge unroll; no max-shift
// (alpha = p * q.k/sqrt(128) is O(1) << 88 -> plain expf f32-safe; softmax shift-invariant)
__global__ __launch_bounds__(256) void attn2_kernel(
    const _Float16* __restrict__ qkv,
    const int* __restrict__ ptr0, const int* __restrict__ csr0,
    const int* __restrict__ ptr1, const int* __restrict__ csr1,
    const float* __restrict__ p0, const float* __restrict__ p1,
    _Float16* __restrict__ att)
{
    const int w = (blockIdx.x * 256 + threadIdx.x) >> 6;
    if (w >= NNODES) return;
    const int lane = threadIdx.x & 63;
    half2v qh = *(const half2v*)(qkv + (size_t)w * 640 + (lane << 1));
    const float qx = (float)qh[0], qy = (float)qh[1];
    float ox = 0.f, oy = 0.f;
    #pragma unroll
    for (int r = 0; r < 2; ++r) {
        const int* ptrv = r ? ptr1 : ptr0;
        const int* csr  = r ? csr1 : csr0;
        const float scale = (r ? p1[0] : p0[0]) * 0.08838834764831845f;
        const int start = ptrv[w], end = ptrv[w + 1];
        if (start == end) continue;
        const _Float16* tbl = qkv + 128 + 256 * r + (lane << 2);
        float denom = 0.f, ax = 0.f, ay = 0.f;
        int i = start;
        for (; i + 8 <= end; i += 8) {
            int s[8];
            #pragma unroll
            for (int j = 0; j < 8; ++j) s[j] = csr[i + j];
            half4 kv[8];
            #pragma unroll
            for (int j = 0; j < 8; ++j) kv[j] = *(const half4*)(tbl + (size_t)s[j] * 640);
            float d[8];
            #pragma unroll
            for (int j = 0; j < 8; ++j) d[j] = qx * (float)kv[j][0] + qy * (float)kv[j][1];
            #pragma unroll
            for (int o2 = 32; o2; o2 >>= 1) {
                #pragma unroll
                for (int j = 0; j < 8; ++j) d[j] += __shfl_xor(d[j], o2, 64);
            }
            #pragma unroll
            for (int j = 0; j < 8; ++j) {
                const float e = __expf(d[j] * scale);
                denom += e;
                ax += e * (float)kv[j][2];
                ay += e * (float)kv[j][3];
            }
        }
        for (; i + 4 <= end; i += 4) {
            const int s0 = csr[i], s1 = csr[i + 1], s2 = csr[i + 2], s3 = csr[i + 3];
            half4 kv0 = *(const half4*)(tbl + (size_t)s0 * 640);
            half4 kv1 = *(const half4*)(tbl + (size_t)s1 * 640);
            half4 kv2 = *(const half4*)(tbl + (size_t)s2 * 640);
            half4 kv3 = *(const half4*)(tbl + (size_t)s3 * 640);
            float d0 = qx * (float)kv0[0] + qy * (float)kv0[1];
            float d1 = qx * (float)kv1[0] + qy * (float)kv1[1];
            float d2 = qx * (float)kv2[0] + qy * (float)kv2[1];
            float d3 = qx * (float)kv3[0] + qy * (float)kv3[1];
            #pragma unroll
            for (int o2 = 32; o2; o2 >>= 1) {
                d0 += __shfl_xor(d0, o2, 64);
                d1 += __shfl_xor(d1, o2, 64);
                d2 += __shfl_xor(d2, o2, 64);
                d3 += __shfl_xor(d3, o2, 64);
            }
            const float e0 = __expf(d0 * scale), e1 = __expf(d1 * scale);
            const float e2 = __expf(d2 * scale), e3 = __expf(d3 * scale);
            denom += (e0 + e1) + (e2 + e3);
            ax += e0 * (float)kv0[2] + e1 * (float)kv1[2] + e2 * (float)kv2[2] + e3 * (float)kv3[2];
            ay += e0 * (float)kv0[3] + e1 * (float)kv1[3] + e2 * (float)kv2[3] + e3 * (float)kv3[3];
        }
        for (; i < end; ++i) {
            const int s = csr[i];
            half4 kv = *(const half4*)(tbl + (size_t)s * 640);
            float d = qx * (float)kv[0] + qy * (float)kv[1];
            #pragma unroll
            for (int o2 = 32; o2; o2 >>= 1) d += __shfl_xor(d, o2, 64);
            const float e = __expf(d * scale);
            denom += e;
            ax += e * (float)kv[2];
            ay += e * (float)kv[3];
        }
        const float inv = 1.0f / denom;
        ox += ax * inv; oy += ay * inv;
    }
    half2v o;
    o[0] = (_Float16)ox;
    o[1] = (_Float16)oy;
    *(half2v*)(att + (size_t)w * HDIM + (lane << 1)) = o;
}

// ---------------- tiny head tail ----------------
__global__ __launch_bounds__(256) void head2_kernel(const _Float16* __restrict__ h,
                                                    const float* __restrict__ Wo2,
                                                    const float* __restrict__ bo2,
                                                    float* __restrict__ out)
{
    int i = blockIdx.x * 256 + threadIdx.x;
    if (i >= NNODES) return;
    const _Float16* hp = h + (size_t)i * 64;
    float s0 = bo2[0], s1 = bo2[1];
    #pragma unroll
    for (int j0 = 0; j0 < 64; j0 += 8) {
        half8 hv = *(const half8*)(hp + j0);
        #pragma unroll
        for (int j = 0; j < 8; ++j) {
            float v = (float)hv[j];
            s0 += v * Wo2[2 * (j0 + j)];
            s1 += v * Wo2[2 * (j0 + j) + 1];
        }
    }
    out[2 * i] = s0;
    out[2 * i + 1] = s1;
}

// ---------------- launch ----------------

extern "C" void kernel_launch(void* const* d_in, const int* in_sizes, int n_in,
                              void* d_out, int out_size, void* d_ws, size_t ws_size,
                              hipStream_t stream)
{
    const float* features = (const float*)d_in[0];
    const int* ei0 = (const int*)d_in[1];
    const int* ei1 = (const int*)d_in[2];
    const float* W1 = (const float*)d_in[3];
    const float* b1 = (const float*)d_in[4];
    const float* Wk = (const float*)d_in[5];
    const float* bk = (const float*)d_in[6];
    const float* Wq = (const float*)d_in[7];
    const float* bq = (const float*)d_in[8];
    const float* Wv = (const float*)d_in[9];
    const float* bv = (const float*)d_in[10];
    const float* A0 = (const float*)d_in[11];
    const float* M0 = (const float*)d_in[12];
    const float* p0 = (const float*)d_in[13];
    const float* A1 = (const float*)d_in[14];
    const float* M1 = (const float*)d_in[15];
    const float* p1 = (const float*)d_in[16];
    const float* Wa = (const float*)d_in[17];
    const float* ba = (const float*)d_in[18];
    const float* skip = (const float*)d_in[19];
    const float* Wo1 = (const float*)d_in[20];
    const float* bo1 = (const float*)d_in[21];
    const float* Wo2 = (const float*)d_in[22];
    const float* bo2 = (const float*)d_in[23];
    (void)in_sizes; (void)n_in; (void)out_size; (void)ws_size;

    char* base = (char*)d_ws;
    size_t off = 0;
    auto alloc = [&](size_t bytes) { size_t r = off; off = (off + bytes + 255) & ~(size_t)255; return base + r; };

    _Float16* x0h  = (_Float16*)alloc((size_t)NNODES * HDIM * 2);
    _Float16* x1h  = (_Float16*)alloc((size_t)NNODES * HDIM * 2);
    _Float16* qkv  = (_Float16*)alloc((size_t)NNODES * 640 * 2);
    _Float16* att  = (_Float16*)alloc((size_t)NNODES * HDIM * 2);
    _Float16* hh   = (_Float16*)alloc((size_t)NNODES * 64 * 2);
    float* WkA[2]  = { (float*)alloc(65536), (float*)alloc(65536) };
    float* WvM[2]  = { (float*)alloc(65536), (float*)alloc(65536) };
    _Float16* WqkvT = (_Float16*)alloc(640 * 128 * 2);
    float*    bqkv  = (float*)   alloc(640 * 4);
    _Float16* W1T   = (_Float16*)alloc(128 * 768 * 2);
    _Float16* WaT   = (_Float16*)alloc(128 * 128 * 2);
    _Float16* Wo1T  = (_Float16*)alloc(64 * 128 * 2);
    // deg0|deg1|fill0|fill1 contiguous -> single memset
    int* zb = (int*)alloc((size_t)4 * NNODES * 4);
    int* deg[2]  = { zb,               zb + NNODES };
    int* fill[2] = { zb + 2 * NNODES,  zb + 3 * NNODES };
    int* ptrv[2] = { (int*)alloc((NNODES + 1) * 4), (int*)alloc((NNODES + 1) * 4) };
    int* csr[2]  = { (int*)alloc(NEDGE * 4),  (int*)alloc(NEDGE * 4) };
    int* sums    = (int*)alloc(2 * 64 * 4);

    // ---- CSR build ----
    hipMemsetAsync(zb, 0, (size_t)4 * NNODES * 4, stream);
    const int egrid = (NEDGE + 255) / 256;
    count2_kernel<<<dim3(egrid, 2), 256, 0, stream>>>(ei0, ei1, deg[0], deg[1]);
    scan1_kernel<<<dim3(NSB, 2), 1024, 0, stream>>>(deg[0], deg[1], ptrv[0], ptrv[1], sums);
    scan2_kernel<<<2, 64, 0, stream>>>(sums, ptrv[0], ptrv[1]);
    scan3_kernel<<<dim3(NSB, 2), 1024, 0, stream>>>(sums, ptrv[0], ptrv[1]);
    scatter2_kernel<<<dim3(egrid, 2), 256, 0, stream>>>(ei0, ei1, ptrv[0], ptrv[1],
                                                        fill[0], fill[1], csr[0], csr[1]);

    // ---- combined relation weights + biases (one dispatch) ----
    cmb_all_kernel<<<dim3(2, 2, 5), 256, 0, stream>>>(Wk, Wv, bk, bv, A0, M0, A1, M1,
                                                      WkA[0], WvM[0], WkA[1], WvM[1], bqkv);

    // ---- pack all fp16 transposed weights (one dispatch) ----
    pack_all_kernel<<<960, 128, 0, stream>>>(Wq, WkA[0], WvM[0], WkA[1], WvM[1],
                                             bq, W1, Wa, Wo1,
                                             WqkvT, bqkv, W1T, WaT, Wo1T);

    const int MBLK = (NNODES + 127) / 128;   // 391
    const int MBLK32 = (NNODES + 31) / 32;   // 1563

    // ---- x0 = leaky(features @ W1 + b1) -> fp16 (BM=128, measured-best structure) ----
    gemm_h<1, 1, false><<<dim3(MBLK, 1), 256, 0, stream>>>(
        features, W1T, b1, nullptr, nullptr, x0h, NNODES, HDIM, FIN);

    // ---- two HGT layers ----
    _Float16* xin = x0h;
    _Float16* xout = x1h;
    for (int layer = 0; layer < 2; ++layer) {
        gemm_h<0, 0, false><<<dim3(MBLK, 5), 256, 0, stream>>>(
            xin, WqkvT, bqkv, nullptr, nullptr, qkv, NNODES, 640, HDIM);
        attn2_kernel<<<(NNODES * 64 + 255) / 256, 256, 0, stream>>>(
            qkv, ptrv[0], csr[0], ptrv[1], csr[1], p0, p1, att);
        gemm_h32<2, 0, true><<<MBLK32, 256, 0, stream>>>(
            att, WaT, ba, xin, skip, xout, NNODES, HDIM, HDIM);
        _Float16* tmp = xin; xin = xout; xout = tmp;
    }

    // ---- head ----
    gemm_h32<1, 0, false><<<MBLK32, 256, 0, stream>>>(
        xin, Wo1T, bo1, nullptr, nullptr, hh, NNODES, 64, HDIM);
    head2_kernel<<<(NNODES + 255) / 256, 256, 0, stream>>>(hh, Wo2, bo2, (float*)d_out);
}